// Round 11
// baseline (126.524 us; speedup 1.0000x reference)
//
#include <hip/hip_runtime.h>
#include <math.h>

#define NN 50000
#define RR 8
#define EE 100000
#define BB 16384
#define ET 800000
#define NB 98                 // coarse buckets per relation (512 nodes each)
#define CAP 2048              // region stride in edges (stored deg <= 2047)
#define OVFCAP 1024

typedef unsigned int uint;
typedef unsigned short ushort;
typedef __attribute__((ext_vector_type(4))) float f32x4;
typedef _Float16 f16x8 __attribute__((ext_vector_type(8)));

// pay4[pos]: (col<<16 | val_fp16), grouped by (r, node) per CSR.
// csr[r*NN+n] = (absStart << 11) | deg. Wfrag: [slot(9)][hi/lo][nfg(8)][ks(4)][lane(64)][8 f16]
// U16: 8 planes of [32768 slots][128] fp16.

// ========== scatterK: verbatim round 9 (passing) ==========
__global__ __launch_bounds__(256) void scatterK(
    const float* __restrict__ emb, const float* __restrict__ rel_k, const float* __restrict__ self_k,
    const int* __restrict__ adj_rows, const int* __restrict__ adj_cols, const float* __restrict__ adj_vals,
    uint* __restrict__ cursor, uint* __restrict__ ovfcnt, uint* __restrict__ ovflist,
    uint2* __restrict__ gpart, ushort* __restrict__ emb16, ushort* __restrict__ Wfrag)
{
    __shared__ int  srow[2000];
    __shared__ int  hist[NB];
    __shared__ uint lbase[NB];
    const int tid = threadIdx.x, bid = blockIdx.x;

    if (bid < 400) {
        const int r  = bid / 50;
        const int e0 = bid * 2000;
        for (int k = tid; k < NB; k += 256) hist[k] = 0;
        __syncthreads();
        for (int i = tid; i < 2000; i += 256) {
            int n = adj_rows[e0 + i];
            srow[i] = n;
            atomicAdd(&hist[n >> 9], 1);
        }
        __syncthreads();
        if (tid < NB) {
            int h = hist[tid];
            lbase[tid] = h ? atomicAdd(&cursor[r * NB + tid], (uint)h) : 0u;
        }
        __syncthreads();
        for (int i = tid; i < 2000; i += 256) {
            int n = srow[i];
            int c = n >> 9;
            uint prel = atomicAdd(&lbase[c], 1u);
            int e = e0 + i;
            ushort v16 = __builtin_bit_cast(ushort, (_Float16)adj_vals[e]);
            uint pay = ((uint)adj_cols[e] << 16) | (uint)v16;
            if (prel < (uint)(CAP - 1)) {
                gpart[(size_t)(r * NB + c) * CAP + prel] = make_uint2(pay, (uint)n);
            } else {
                uint o = atomicAdd(ovfcnt, 1u);
                if (o < OVFCAP) ovflist[o] = (uint)e;
            }
        }
    } else if (bid < 791) {
        int b = bid - 400;
        #pragma unroll
        for (int i = 0; i < 16; i++) {
            int c = i * 256 + tid;
            int row = b * 128 + (c >> 5);
            if (row < NN) {
                int k4 = (c & 31) * 4;
                float4 v = *(const float4*)(emb + (size_t)row * 128 + k4);
                _Float16 h4[4] = {(_Float16)v.x, (_Float16)v.y, (_Float16)v.z, (_Float16)v.w};
                *(ulonglong1*)(emb16 + (size_t)row * 128 + k4) = *(ulonglong1*)h4;
            }
        }
    } else {
        int r = bid - 791;
        const float* src = (r < RR) ? rel_k + (size_t)r * 128 * 128 : self_k;
        #pragma unroll
        for (int q = 0; q < 8; q++) {
            int ls = q * 256 + tid;
            int nfg = ls >> 8, ks = (ls >> 6) & 3, lane = ls & 63;
            int n = nfg * 16 + (lane & 15);
            int k0 = ks * 32 + (lane >> 4) * 8;
            f16x8 hi, lo;
            #pragma unroll
            for (int j = 0; j < 8; j++) {
                float x = src[(size_t)(k0 + j) * 128 + n];
                _Float16 h = (_Float16)x;
                hi[j] = h;
                lo[j] = (_Float16)(x - (float)h);
            }
            size_t bo = (size_t)(r * 2) * 16384 + (size_t)(nfg * 4 + ks) * 512 + (size_t)lane * 8;
            *(f16x8*)(Wfrag + bo)         = hi;
            *(f16x8*)(Wfrag + 16384 + bo) = lo;
        }
    }
}

// ========== groupK: verbatim round 9 (passing) ==========
__global__ __launch_bounds__(256) void groupK(
    const uint* __restrict__ cursor, const uint2* __restrict__ gpart,
    uint* __restrict__ pay4, uint* __restrict__ csr)
{
    __shared__ ushort skey[CAP];
    __shared__ uint   spin[CAP];
    __shared__ uint   ssort[CAP];
    __shared__ int    cnt2[512];
    __shared__ int    sa[512], sb[512];
    __shared__ int    cur2[512];
    const int tid = threadIdx.x, rc = blockIdx.x;
    const int c = rc % NB, r = rc / NB;
    const int nodes0 = c * 512;
    const int nnodes = (c == NB - 1) ? (NN - nodes0) : 512;
    uint cntv = cursor[rc]; if (cntv > (uint)(CAP - 1)) cntv = CAP - 1;
    const int cnt = (int)cntv;

    for (int k = tid; k < 512; k += 256) cnt2[k] = 0;
    __syncthreads();
    for (int i = tid; i < cnt; i += 256) {
        uint2 p = gpart[(size_t)rc * CAP + i];
        int key = (int)p.y - nodes0;
        skey[i] = (ushort)key;
        spin[i] = p.x;
        atomicAdd(&cnt2[key], 1);
    }
    __syncthreads();
    for (int k = tid; k < 512; k += 256) sa[k] = cnt2[k];
    __syncthreads();
    int* src = sa; int* dst = sb;
    for (int d = 1; d < 512; d <<= 1) {
        for (int k = tid; k < 512; k += 256)
            dst[k] = src[k] + (k >= d ? src[k - d] : 0);
        __syncthreads();
        int* t = src; src = dst; dst = t;
    }
    for (int k = tid; k < 512; k += 256) cur2[k] = k ? src[k - 1] : 0;
    __syncthreads();
    for (int i = tid; i < cnt; i += 256) {
        int p = atomicAdd(&cur2[skey[i]], 1);
        ssort[p] = spin[i];
    }
    __syncthreads();
    for (int i = tid; i < cnt; i += 256)
        pay4[(size_t)rc * CAP + i] = ssort[i];
    for (int j = tid; j < nnodes; j += 256) {
        uint start = (uint)rc * CAP + (uint)(j ? src[j - 1] : 0);
        csr[r * NN + nodes0 + j] = (start << 11) | (uint)cnt2[j];
    }
}

// ========== gatherU v4: one WAVE per (slot, r); 4-way intra-wave edge parallelism ==========
// grid 65536 x 256 (4 waves/block). wv = bid*4 + wave; r = wv>>15; slot = wv & 32767.
// Wave's 4 groups of 16 lanes take edge indices i ≡ g (mod 4); shfl_xor(16,32) tree-reduce.
__global__ __launch_bounds__(256, 8) void gatherU(
    const int* __restrict__ head_idx, const int* __restrict__ tail_idx,
    const uint* __restrict__ csr, const uint* __restrict__ pay4,
    const int* __restrict__ adj_rows, const int* __restrict__ adj_cols, const float* __restrict__ adj_vals,
    const uint* __restrict__ ovfcnt, const uint* __restrict__ ovflist,
    const ushort* __restrict__ emb16, ushort* __restrict__ U16)
{
    const int tid = threadIdx.x;
    const int wv = blockIdx.x * 4 + (tid >> 6);
    const int r = wv >> 15;
    const int slot = wv & 32767;
    const int l16 = tid & 15;
    const int g4 = (tid >> 4) & 3;

    int n = (slot < BB) ? head_idx[slot] : tail_idx[slot - BB];
    uint cd = csr[r * NN + n];
    uint s = cd >> 11;
    int deg = (int)(cd & 2047u);

    float a[8] = {0.f,0.f,0.f,0.f,0.f,0.f,0.f,0.f};
    for (int i = g4; i < deg; i += 4) {           // groups cover 4 edges concurrently
        uint p = pay4[s + i];
        float v = (float)__builtin_bit_cast(_Float16, (ushort)(p & 0xFFFFu));
        f16x8 em = *(const f16x8*)(emb16 + (size_t)(p >> 16) * 128 + l16 * 8);
        #pragma unroll
        for (int q = 0; q < 8; q++) a[q] = fmaf(v, (float)em[q], a[q]);
    }

    if (g4 == 0) {                                // overflow insurance (novf==0 in practice)
        uint novf = *ovfcnt; if (novf > OVFCAP) novf = OVFCAP;
        for (uint o = 0; o < novf; o++) {
            uint e = ovflist[o];
            int re = (int)(e / EE);
            if (re == r && adj_rows[e] == n) {
                float v = adj_vals[e];
                f16x8 em = *(const f16x8*)(emb16 + (size_t)adj_cols[e] * 128 + l16 * 8);
                #pragma unroll
                for (int q = 0; q < 8; q++) a[q] = fmaf(v, (float)em[q], a[q]);
            }
        }
    }

    // tree-reduce the 4 groups' partials (lanes with equal l16)
    #pragma unroll
    for (int q = 0; q < 8; q++) {
        a[q] += __shfl_xor(a[q], 16);
        a[q] += __shfl_xor(a[q], 32);
    }

    if (g4 == 0) {
        f16x8 uu;
        #pragma unroll
        for (int q = 0; q < 8; q++) uu[q] = (_Float16)a[q];
        *(f16x8*)(U16 + ((size_t)r * 32768 + slot) * 128 + l16 * 8) = uu;
    }
}

// =================== gemm: verbatim rounds 8/9 (passing) ===================
__global__ __launch_bounds__(256) void gemm(
    const float* __restrict__ head_e, const float* __restrict__ tail_e,
    const ushort* __restrict__ U16, const ushort* __restrict__ Wfrag,
    float* __restrict__ out)
{
    __shared__ char sA[3][16384];
    const int tid = threadIdx.x, bid = blockIdx.x;
    const int w = tid >> 6, l = tid & 63;
    const int lr = l & 15, kq = l >> 4;
    const int nfg0 = w * 2;

    f32x4 acc[4][2];
    #pragma unroll
    for (int a = 0; a < 4; a++)
        #pragma unroll
        for (int b = 0; b < 2; b++) acc[a][b] = (f32x4){0.f, 0.f, 0.f, 0.f};

    const float* S = (bid < 256) ? head_e + (size_t)bid * 64 * 128
                                 : tail_e + (size_t)(bid - 256) * 64 * 128;
    #pragma unroll
    for (int i = 0; i < 4; i++) {
        int c = i * 256 + tid;
        int row = c >> 4;
        int k8 = (c & 15) * 8;
        float4 v0 = *(const float4*)(S + (size_t)row * 128 + k8);
        float4 v1 = *(const float4*)(S + (size_t)row * 128 + k8 + 4);
        float xs[8] = {v0.x, v0.y, v0.z, v0.w, v1.x, v1.y, v1.z, v1.w};
        f16x8 h, lo;
        #pragma unroll
        for (int j = 0; j < 8; j++) {
            _Float16 hh = (_Float16)xs[j];
            h[j] = hh;
            lo[j] = (_Float16)(xs[j] - (float)hh);
        }
        int off = row * 256 + ((k8 * 2) ^ ((row & 7) << 4));
        *(f16x8*)(sA[0] + off) = h;
        *(f16x8*)(sA[1] + off) = lo;
    }
    __syncthreads();

    float4 pf0, pf1, pf2, pf3;
    const char* Ub = (const char*)U16 + (size_t)bid * 64 * 256;

    #define STAGE(r) {                                                          \
        const char* gp = Ub + (size_t)(r) * 32768 * 256;                        \
        pf0 = *(const float4*)(gp + (0 * 256 + tid) * 16);                      \
        pf1 = *(const float4*)(gp + (1 * 256 + tid) * 16);                      \
        pf2 = *(const float4*)(gp + (2 * 256 + tid) * 16);                      \
        pf3 = *(const float4*)(gp + (3 * 256 + tid) * 16);                      \
    }
    #define WRITE(buf) {                                                        \
        _Pragma("unroll")                                                       \
        for (int i = 0; i < 4; i++) {                                           \
            int c = i * 256 + tid;                                              \
            int row = c >> 4, cc = c & 15;                                      \
            int off = row * 256 + ((cc * 16) ^ ((row & 7) << 4));               \
            *(float4*)(sA[buf] + off) = (i==0)?pf0:(i==1)?pf1:(i==2)?pf2:pf3;   \
        }                                                                       \
    }

    STAGE(0);
    {
        const ushort* Wb = Wfrag + (size_t)(8 * 2) * 16384;
        #pragma unroll
        for (int ks = 0; ks < 4; ks++) {
            int kb = ks * 64 + kq * 16;
            f16x8 ah[4], al[4], bh[2], bl[2];
            #pragma unroll
            for (int nf = 0; nf < 2; nf++) {
                size_t bo = (size_t)(((nfg0 + nf) * 4 + ks) * 64 + l) * 8;
                bh[nf] = *(const f16x8*)(Wb + bo);
                bl[nf] = *(const f16x8*)(Wb + 16384 + bo);
            }
            #pragma unroll
            for (int mf = 0; mf < 4; mf++) {
                int row = mf * 16 + lr;
                int off = row * 256 + (kb ^ ((row & 7) << 4));
                ah[mf] = *(const f16x8*)(sA[0] + off);
                al[mf] = *(const f16x8*)(sA[1] + off);
            }
            #pragma unroll
            for (int mf = 0; mf < 4; mf++)
                #pragma unroll
                for (int nf = 0; nf < 2; nf++) {
                    acc[mf][nf] = __builtin_amdgcn_mfma_f32_16x16x32_f16(ah[mf], bh[nf], acc[mf][nf], 0, 0, 0);
                    acc[mf][nf] = __builtin_amdgcn_mfma_f32_16x16x32_f16(ah[mf], bl[nf], acc[mf][nf], 0, 0, 0);
                    acc[mf][nf] = __builtin_amdgcn_mfma_f32_16x16x32_f16(al[mf], bh[nf], acc[mf][nf], 0, 0, 0);
                }
        }
    }
    WRITE(2);
    __syncthreads();

    for (int r = 0; r < RR; r++) {
        if (r < 7) STAGE(r + 1);
        const ushort* Wb = Wfrag + (size_t)(r * 2) * 16384;
        const char* bufp = sA[(r + 2) % 3];
        #pragma unroll
        for (int ks = 0; ks < 4; ks++) {
            int kb = ks * 64 + kq * 16;
            f16x8 av[4], bh[2], bl[2];
            #pragma unroll
            for (int nf = 0; nf < 2; nf++) {
                size_t bo = (size_t)(((nfg0 + nf) * 4 + ks) * 64 + l) * 8;
                bh[nf] = *(const f16x8*)(Wb + bo);
                bl[nf] = *(const f16x8*)(Wb + 16384 + bo);
            }
            #pragma unroll
            for (int mf = 0; mf < 4; mf++) {
                int row = mf * 16 + lr;
                av[mf] = *(const f16x8*)(bufp + row * 256 + (kb ^ ((row & 7) << 4)));
            }
            #pragma unroll
            for (int mf = 0; mf < 4; mf++)
                #pragma unroll
                for (int nf = 0; nf < 2; nf++) {
                    acc[mf][nf] = __builtin_amdgcn_mfma_f32_16x16x32_f16(av[mf], bh[nf], acc[mf][nf], 0, 0, 0);
                    acc[mf][nf] = __builtin_amdgcn_mfma_f32_16x16x32_f16(av[mf], bl[nf], acc[mf][nf], 0, 0, 0);
                }
        }
        if (r < 7) {
            WRITE(r % 3);
            __syncthreads();
        }
    }

    #pragma unroll
    for (int mf = 0; mf < 4; mf++)
        #pragma unroll
        for (int j = 0; j < 4; j++) {
            int lrow = mf * 16 + kq * 4 + j;
            size_t slot = (size_t)bid * 64 + lrow;
            #pragma unroll
            for (int nf = 0; nf < 2; nf++) {
                int col = (nfg0 + nf) * 16 + lr;
                float x = acc[mf][nf][j];
                out[slot * 128 + col] = 1.f / (1.f + __expf(-x));
            }
        }
    #undef STAGE
    #undef WRITE
}

extern "C" void kernel_launch(void* const* d_in, const int* in_sizes, int n_in,
                              void* d_out, int out_size, void* d_ws, size_t ws_size,
                              hipStream_t stream)
{
    const float* embeddings = (const float*)d_in[0];
    const int*   head_idx   = (const int*)d_in[1];
    const float* head_e     = (const float*)d_in[2];
    const int*   tail_idx   = (const int*)d_in[3];
    const float* tail_e     = (const float*)d_in[4];
    const int*   adj_rows   = (const int*)d_in[5];
    const int*   adj_cols   = (const int*)d_in[6];
    const float* adj_vals   = (const float*)d_in[7];
    const float* rel_k      = (const float*)d_in[8];
    const float* self_k     = (const float*)d_in[9];
    float* out = (float*)d_out;

    // workspace layout (~101.4 MB)
    char* ws = (char*)d_ws;
    uint*   cursor  = (uint*)ws;                      //   3,136 B (784)
    uint*   ovfcnt  = (uint*)(ws + 3136);             //       4 B
    uint*   ovflist = (uint*)(ws + 3140);             //   4,096 B
    ushort* Wfrag   = (ushort*)(ws + 8192);           //     589,824 B
    ushort* emb16   = (ushort*)(ws + 598016);         //  12,800,000 B
    uint*   csr     = (uint*)(ws + 13398016);         //   1,600,000 B
    uint*   pay4    = (uint*)(ws + 14998016);         //   6,422,528 B
    uint2*  gpart   = (uint2*)(ws + 21420544);        //  12,845,056 B
    ushort* U16     = (ushort*)(ws + 34265600);       //  67,108,864 B

    hipMemsetAsync(cursor, 0, 3140, stream);          // cursor + ovfcnt

    scatterK<<<800, 256, 0, stream>>>(embeddings, rel_k, self_k,
                                      adj_rows, adj_cols, adj_vals,
                                      cursor, ovfcnt, ovflist, gpart, emb16, Wfrag);

    groupK<<<784, 256, 0, stream>>>(cursor, gpart, pay4, csr);

    gatherU<<<65536, 256, 0, stream>>>(head_idx, tail_idx, csr, pay4,
                                       adj_rows, adj_cols, adj_vals,
                                       ovfcnt, ovflist, emb16, U16);

    gemm<<<512, 256, 0, stream>>>(head_e, tail_e, U16, Wfrag, out);
}

// Round 12
// 91.814 us; speedup vs baseline: 1.3781x; 1.3781x over previous
//
#include <hip/hip_runtime.h>
#include <math.h>

#define NN 50000
#define RR 8
#define EE 100000
#define BB 16384
#define ET 800000
#define NB 98                 // coarse buckets per relation (512 nodes each)
#define CAP 2048              // region stride in edges (stored deg <= 2047)
#define OVFCAP 1024

typedef unsigned int uint;
typedef unsigned short ushort;
typedef __attribute__((ext_vector_type(4))) float f32x4;
typedef _Float16 f16x8 __attribute__((ext_vector_type(8)));

// pay4[pos]: (col<<16 | val_fp16), grouped by (r, node) per CSR.
// csr[r*NN+n] = (absStart << 11) | deg. Wfrag: [slot(9)][hi/lo][nfg(8)][ks(4)][lane(64)][8 f16]
// U16: 8 planes of [32768 slots][128] fp16.

// ========== scatterK: verbatim round 9 (passing) ==========
__global__ __launch_bounds__(256) void scatterK(
    const float* __restrict__ emb, const float* __restrict__ rel_k, const float* __restrict__ self_k,
    const int* __restrict__ adj_rows, const int* __restrict__ adj_cols, const float* __restrict__ adj_vals,
    uint* __restrict__ cursor, uint* __restrict__ ovfcnt, uint* __restrict__ ovflist,
    uint2* __restrict__ gpart, ushort* __restrict__ emb16, ushort* __restrict__ Wfrag)
{
    __shared__ int  srow[2000];
    __shared__ int  hist[NB];
    __shared__ uint lbase[NB];
    const int tid = threadIdx.x, bid = blockIdx.x;

    if (bid < 400) {
        const int r  = bid / 50;
        const int e0 = bid * 2000;
        for (int k = tid; k < NB; k += 256) hist[k] = 0;
        __syncthreads();
        for (int i = tid; i < 2000; i += 256) {
            int n = adj_rows[e0 + i];
            srow[i] = n;
            atomicAdd(&hist[n >> 9], 1);
        }
        __syncthreads();
        if (tid < NB) {
            int h = hist[tid];
            lbase[tid] = h ? atomicAdd(&cursor[r * NB + tid], (uint)h) : 0u;
        }
        __syncthreads();
        for (int i = tid; i < 2000; i += 256) {
            int n = srow[i];
            int c = n >> 9;
            uint prel = atomicAdd(&lbase[c], 1u);
            int e = e0 + i;
            ushort v16 = __builtin_bit_cast(ushort, (_Float16)adj_vals[e]);
            uint pay = ((uint)adj_cols[e] << 16) | (uint)v16;
            if (prel < (uint)(CAP - 1)) {
                gpart[(size_t)(r * NB + c) * CAP + prel] = make_uint2(pay, (uint)n);
            } else {
                uint o = atomicAdd(ovfcnt, 1u);
                if (o < OVFCAP) ovflist[o] = (uint)e;
            }
        }
    } else if (bid < 791) {
        int b = bid - 400;
        #pragma unroll
        for (int i = 0; i < 16; i++) {
            int c = i * 256 + tid;
            int row = b * 128 + (c >> 5);
            if (row < NN) {
                int k4 = (c & 31) * 4;
                float4 v = *(const float4*)(emb + (size_t)row * 128 + k4);
                _Float16 h4[4] = {(_Float16)v.x, (_Float16)v.y, (_Float16)v.z, (_Float16)v.w};
                *(ulonglong1*)(emb16 + (size_t)row * 128 + k4) = *(ulonglong1*)h4;
            }
        }
    } else {
        int r = bid - 791;
        const float* src = (r < RR) ? rel_k + (size_t)r * 128 * 128 : self_k;
        #pragma unroll
        for (int q = 0; q < 8; q++) {
            int ls = q * 256 + tid;
            int nfg = ls >> 8, ks = (ls >> 6) & 3, lane = ls & 63;
            int n = nfg * 16 + (lane & 15);
            int k0 = ks * 32 + (lane >> 4) * 8;
            f16x8 hi, lo;
            #pragma unroll
            for (int j = 0; j < 8; j++) {
                float x = src[(size_t)(k0 + j) * 128 + n];
                _Float16 h = (_Float16)x;
                hi[j] = h;
                lo[j] = (_Float16)(x - (float)h);
            }
            size_t bo = (size_t)(r * 2) * 16384 + (size_t)(nfg * 4 + ks) * 512 + (size_t)lane * 8;
            *(f16x8*)(Wfrag + bo)         = hi;
            *(f16x8*)(Wfrag + 16384 + bo) = lo;
        }
    }
}

// ========== groupK: verbatim round 9 (passing) ==========
__global__ __launch_bounds__(256) void groupK(
    const uint* __restrict__ cursor, const uint2* __restrict__ gpart,
    uint* __restrict__ pay4, uint* __restrict__ csr)
{
    __shared__ ushort skey[CAP];
    __shared__ uint   spin[CAP];
    __shared__ uint   ssort[CAP];
    __shared__ int    cnt2[512];
    __shared__ int    sa[512], sb[512];
    __shared__ int    cur2[512];
    const int tid = threadIdx.x, rc = blockIdx.x;
    const int c = rc % NB, r = rc / NB;
    const int nodes0 = c * 512;
    const int nnodes = (c == NB - 1) ? (NN - nodes0) : 512;
    uint cntv = cursor[rc]; if (cntv > (uint)(CAP - 1)) cntv = CAP - 1;
    const int cnt = (int)cntv;

    for (int k = tid; k < 512; k += 256) cnt2[k] = 0;
    __syncthreads();
    for (int i = tid; i < cnt; i += 256) {
        uint2 p = gpart[(size_t)rc * CAP + i];
        int key = (int)p.y - nodes0;
        skey[i] = (ushort)key;
        spin[i] = p.x;
        atomicAdd(&cnt2[key], 1);
    }
    __syncthreads();
    for (int k = tid; k < 512; k += 256) sa[k] = cnt2[k];
    __syncthreads();
    int* src = sa; int* dst = sb;
    for (int d = 1; d < 512; d <<= 1) {
        for (int k = tid; k < 512; k += 256)
            dst[k] = src[k] + (k >= d ? src[k - d] : 0);
        __syncthreads();
        int* t = src; src = dst; dst = t;
    }
    for (int k = tid; k < 512; k += 256) cur2[k] = k ? src[k - 1] : 0;
    __syncthreads();
    for (int i = tid; i < cnt; i += 256) {
        int p = atomicAdd(&cur2[skey[i]], 1);
        ssort[p] = spin[i];
    }
    __syncthreads();
    for (int i = tid; i < cnt; i += 256)
        pay4[(size_t)rc * CAP + i] = ssort[i];
    for (int j = tid; j < nnodes; j += 256) {
        uint start = (uint)rc * CAP + (uint)(j ? src[j - 1] : 0);
        csr[r * NN + nodes0 + j] = (start << 11) | (uint)cnt2[j];
    }
}

// ========== gatherU v5: v3 structure (16-lane group per (slot,r)) + 4-way MLP in degree loop ==========
// grid 16384 x 256: bid>>11 = r; 16 consecutive slots per block -> coalesced U writes.
// Lane l16 pre-loads pay4[s+l16] (one coalesced 64B/group); chunks of 4 edges broadcast
// via __shfl(.,i,16); all 4 emb loads issue before FMAs. FMA order identical to v3.
__global__ __launch_bounds__(256, 8) void gatherU(
    const int* __restrict__ head_idx, const int* __restrict__ tail_idx,
    const uint* __restrict__ csr, const uint* __restrict__ pay4,
    const int* __restrict__ adj_rows, const int* __restrict__ adj_cols, const float* __restrict__ adj_vals,
    const uint* __restrict__ ovfcnt, const uint* __restrict__ ovflist,
    const ushort* __restrict__ emb16, ushort* __restrict__ U16)
{
    const int tid = threadIdx.x, bid = blockIdx.x;
    const int g16 = tid >> 4, l16 = tid & 15;
    const int r = bid >> 11;
    const int slot = (bid & 2047) * 16 + g16;
    int n = (slot < BB) ? head_idx[slot] : tail_idx[slot - BB];
    uint cd = csr[r * NN + n];
    uint s = cd >> 11;
    int deg = (int)(cd & 2047u);

    uint pv = 0;
    if (l16 < deg) pv = pay4[s + l16];            // coalesced 64B per group

    float a[8] = {0.f,0.f,0.f,0.f,0.f,0.f,0.f,0.f};
    const int dmain = deg < 16 ? deg : 16;
    for (int i0 = 0; i0 < dmain; i0 += 4) {
        const int m = dmain - i0;                 // 1..4, uniform per group
        uint p0 = __shfl(pv, i0 + 0, 16);
        uint p1 = __shfl(pv, i0 + 1, 16);
        uint p2 = __shfl(pv, i0 + 2, 16);
        uint p3 = __shfl(pv, i0 + 3, 16);
        f16x8 e0, e1, e2, e3;
        e0 = *(const f16x8*)(emb16 + (size_t)(p0 >> 16) * 128 + l16 * 8);
        if (m > 1) e1 = *(const f16x8*)(emb16 + (size_t)(p1 >> 16) * 128 + l16 * 8);
        if (m > 2) e2 = *(const f16x8*)(emb16 + (size_t)(p2 >> 16) * 128 + l16 * 8);
        if (m > 3) e3 = *(const f16x8*)(emb16 + (size_t)(p3 >> 16) * 128 + l16 * 8);
        {
            float v = (float)__builtin_bit_cast(_Float16, (ushort)(p0 & 0xFFFFu));
            #pragma unroll
            for (int q = 0; q < 8; q++) a[q] = fmaf(v, (float)e0[q], a[q]);
        }
        if (m > 1) {
            float v = (float)__builtin_bit_cast(_Float16, (ushort)(p1 & 0xFFFFu));
            #pragma unroll
            for (int q = 0; q < 8; q++) a[q] = fmaf(v, (float)e1[q], a[q]);
        }
        if (m > 2) {
            float v = (float)__builtin_bit_cast(_Float16, (ushort)(p2 & 0xFFFFu));
            #pragma unroll
            for (int q = 0; q < 8; q++) a[q] = fmaf(v, (float)e2[q], a[q]);
        }
        if (m > 3) {
            float v = (float)__builtin_bit_cast(_Float16, (ushort)(p3 & 0xFFFFu));
            #pragma unroll
            for (int q = 0; q < 8; q++) a[q] = fmaf(v, (float)e3[q], a[q]);
        }
    }
    for (int i = 16; i < deg; i++) {              // tail (P ~ 1e-9, correctness only)
        uint p = pay4[s + i];
        float v = (float)__builtin_bit_cast(_Float16, (ushort)(p & 0xFFFFu));
        f16x8 em = *(const f16x8*)(emb16 + (size_t)(p >> 16) * 128 + l16 * 8);
        #pragma unroll
        for (int q = 0; q < 8; q++) a[q] = fmaf(v, (float)em[q], a[q]);
    }
    // overflow insurance (novf == 0 in practice)
    uint novf = *ovfcnt; if (novf > OVFCAP) novf = OVFCAP;
    for (uint o = 0; o < novf; o++) {
        uint e = ovflist[o];
        int re = (int)(e / EE);
        if (re == r && adj_rows[e] == n) {
            float v = adj_vals[e];
            f16x8 em = *(const f16x8*)(emb16 + (size_t)adj_cols[e] * 128 + l16 * 8);
            #pragma unroll
            for (int q = 0; q < 8; q++) a[q] = fmaf(v, (float)em[q], a[q]);
        }
    }
    f16x8 uu;
    #pragma unroll
    for (int q = 0; q < 8; q++) uu[q] = (_Float16)a[q];
    *(f16x8*)(U16 + ((size_t)r * 32768 + slot) * 128 + l16 * 8) = uu;
}

// =================== gemm: verbatim rounds 8/9 (passing) ===================
__global__ __launch_bounds__(256) void gemm(
    const float* __restrict__ head_e, const float* __restrict__ tail_e,
    const ushort* __restrict__ U16, const ushort* __restrict__ Wfrag,
    float* __restrict__ out)
{
    __shared__ char sA[3][16384];
    const int tid = threadIdx.x, bid = blockIdx.x;
    const int w = tid >> 6, l = tid & 63;
    const int lr = l & 15, kq = l >> 4;
    const int nfg0 = w * 2;

    f32x4 acc[4][2];
    #pragma unroll
    for (int a = 0; a < 4; a++)
        #pragma unroll
        for (int b = 0; b < 2; b++) acc[a][b] = (f32x4){0.f, 0.f, 0.f, 0.f};

    const float* S = (bid < 256) ? head_e + (size_t)bid * 64 * 128
                                 : tail_e + (size_t)(bid - 256) * 64 * 128;
    #pragma unroll
    for (int i = 0; i < 4; i++) {
        int c = i * 256 + tid;
        int row = c >> 4;
        int k8 = (c & 15) * 8;
        float4 v0 = *(const float4*)(S + (size_t)row * 128 + k8);
        float4 v1 = *(const float4*)(S + (size_t)row * 128 + k8 + 4);
        float xs[8] = {v0.x, v0.y, v0.z, v0.w, v1.x, v1.y, v1.z, v1.w};
        f16x8 h, lo;
        #pragma unroll
        for (int j = 0; j < 8; j++) {
            _Float16 hh = (_Float16)xs[j];
            h[j] = hh;
            lo[j] = (_Float16)(xs[j] - (float)hh);
        }
        int off = row * 256 + ((k8 * 2) ^ ((row & 7) << 4));
        *(f16x8*)(sA[0] + off) = h;
        *(f16x8*)(sA[1] + off) = lo;
    }
    __syncthreads();

    float4 pf0, pf1, pf2, pf3;
    const char* Ub = (const char*)U16 + (size_t)bid * 64 * 256;

    #define STAGE(r) {                                                          \
        const char* gp = Ub + (size_t)(r) * 32768 * 256;                        \
        pf0 = *(const float4*)(gp + (0 * 256 + tid) * 16);                      \
        pf1 = *(const float4*)(gp + (1 * 256 + tid) * 16);                      \
        pf2 = *(const float4*)(gp + (2 * 256 + tid) * 16);                      \
        pf3 = *(const float4*)(gp + (3 * 256 + tid) * 16);                      \
    }
    #define WRITE(buf) {                                                        \
        _Pragma("unroll")                                                       \
        for (int i = 0; i < 4; i++) {                                           \
            int c = i * 256 + tid;                                              \
            int row = c >> 4, cc = c & 15;                                      \
            int off = row * 256 + ((cc * 16) ^ ((row & 7) << 4));               \
            *(float4*)(sA[buf] + off) = (i==0)?pf0:(i==1)?pf1:(i==2)?pf2:pf3;   \
        }                                                                       \
    }

    STAGE(0);
    {
        const ushort* Wb = Wfrag + (size_t)(8 * 2) * 16384;
        #pragma unroll
        for (int ks = 0; ks < 4; ks++) {
            int kb = ks * 64 + kq * 16;
            f16x8 ah[4], al[4], bh[2], bl[2];
            #pragma unroll
            for (int nf = 0; nf < 2; nf++) {
                size_t bo = (size_t)(((nfg0 + nf) * 4 + ks) * 64 + l) * 8;
                bh[nf] = *(const f16x8*)(Wb + bo);
                bl[nf] = *(const f16x8*)(Wb + 16384 + bo);
            }
            #pragma unroll
            for (int mf = 0; mf < 4; mf++) {
                int row = mf * 16 + lr;
                int off = row * 256 + (kb ^ ((row & 7) << 4));
                ah[mf] = *(const f16x8*)(sA[0] + off);
                al[mf] = *(const f16x8*)(sA[1] + off);
            }
            #pragma unroll
            for (int mf = 0; mf < 4; mf++)
                #pragma unroll
                for (int nf = 0; nf < 2; nf++) {
                    acc[mf][nf] = __builtin_amdgcn_mfma_f32_16x16x32_f16(ah[mf], bh[nf], acc[mf][nf], 0, 0, 0);
                    acc[mf][nf] = __builtin_amdgcn_mfma_f32_16x16x32_f16(ah[mf], bl[nf], acc[mf][nf], 0, 0, 0);
                    acc[mf][nf] = __builtin_amdgcn_mfma_f32_16x16x32_f16(al[mf], bh[nf], acc[mf][nf], 0, 0, 0);
                }
        }
    }
    WRITE(2);
    __syncthreads();

    for (int r = 0; r < RR; r++) {
        if (r < 7) STAGE(r + 1);
        const ushort* Wb = Wfrag + (size_t)(r * 2) * 16384;
        const char* bufp = sA[(r + 2) % 3];
        #pragma unroll
        for (int ks = 0; ks < 4; ks++) {
            int kb = ks * 64 + kq * 16;
            f16x8 av[4], bh[2], bl[2];
            #pragma unroll
            for (int nf = 0; nf < 2; nf++) {
                size_t bo = (size_t)(((nfg0 + nf) * 4 + ks) * 64 + l) * 8;
                bh[nf] = *(const f16x8*)(Wb + bo);
                bl[nf] = *(const f16x8*)(Wb + 16384 + bo);
            }
            #pragma unroll
            for (int mf = 0; mf < 4; mf++) {
                int row = mf * 16 + lr;
                av[mf] = *(const f16x8*)(bufp + row * 256 + (kb ^ ((row & 7) << 4)));
            }
            #pragma unroll
            for (int mf = 0; mf < 4; mf++)
                #pragma unroll
                for (int nf = 0; nf < 2; nf++) {
                    acc[mf][nf] = __builtin_amdgcn_mfma_f32_16x16x32_f16(av[mf], bh[nf], acc[mf][nf], 0, 0, 0);
                    acc[mf][nf] = __builtin_amdgcn_mfma_f32_16x16x32_f16(av[mf], bl[nf], acc[mf][nf], 0, 0, 0);
                }
        }
        if (r < 7) {
            WRITE(r % 3);
            __syncthreads();
        }
    }

    #pragma unroll
    for (int mf = 0; mf < 4; mf++)
        #pragma unroll
        for (int j = 0; j < 4; j++) {
            int lrow = mf * 16 + kq * 4 + j;
            size_t slot = (size_t)bid * 64 + lrow;
            #pragma unroll
            for (int nf = 0; nf < 2; nf++) {
                int col = (nfg0 + nf) * 16 + lr;
                float x = acc[mf][nf][j];
                out[slot * 128 + col] = 1.f / (1.f + __expf(-x));
            }
        }
    #undef STAGE
    #undef WRITE
}

extern "C" void kernel_launch(void* const* d_in, const int* in_sizes, int n_in,
                              void* d_out, int out_size, void* d_ws, size_t ws_size,
                              hipStream_t stream)
{
    const float* embeddings = (const float*)d_in[0];
    const int*   head_idx   = (const int*)d_in[1];
    const float* head_e     = (const float*)d_in[2];
    const int*   tail_idx   = (const int*)d_in[3];
    const float* tail_e     = (const float*)d_in[4];
    const int*   adj_rows   = (const int*)d_in[5];
    const int*   adj_cols   = (const int*)d_in[6];
    const float* adj_vals   = (const float*)d_in[7];
    const float* rel_k      = (const float*)d_in[8];
    const float* self_k     = (const float*)d_in[9];
    float* out = (float*)d_out;

    // workspace layout (~101.4 MB)
    char* ws = (char*)d_ws;
    uint*   cursor  = (uint*)ws;                      //   3,136 B (784)
    uint*   ovfcnt  = (uint*)(ws + 3136);             //       4 B
    uint*   ovflist = (uint*)(ws + 3140);             //   4,096 B
    ushort* Wfrag   = (ushort*)(ws + 8192);           //     589,824 B
    ushort* emb16   = (ushort*)(ws + 598016);         //  12,800,000 B
    uint*   csr     = (uint*)(ws + 13398016);         //   1,600,000 B
    uint*   pay4    = (uint*)(ws + 14998016);         //   6,422,528 B
    uint2*  gpart   = (uint2*)(ws + 21420544);        //  12,845,056 B
    ushort* U16     = (ushort*)(ws + 34265600);       //  67,108,864 B

    hipMemsetAsync(cursor, 0, 3140, stream);          // cursor + ovfcnt

    scatterK<<<800, 256, 0, stream>>>(embeddings, rel_k, self_k,
                                      adj_rows, adj_cols, adj_vals,
                                      cursor, ovfcnt, ovflist, gpart, emb16, Wfrag);

    groupK<<<784, 256, 0, stream>>>(cursor, gpart, pay4, csr);

    gatherU<<<16384, 256, 0, stream>>>(head_idx, tail_idx, csr, pay4,
                                       adj_rows, adj_cols, adj_vals,
                                       ovfcnt, ovflist, emb16, U16);

    gemm<<<512, 256, 0, stream>>>(head_e, tail_e, U16, Wfrag, out);
}